// Round 2
// 404.176 us; speedup vs baseline: 1.1218x; 1.1218x over previous
//
#include <hip/hip_runtime.h>
#include <hip/hip_bf16.h>

typedef short bf16x8 __attribute__((ext_vector_type(8)));
typedef float f32x4  __attribute__((ext_vector_type(4)));

#define SEQ   2048
#define HD    64
#define LDT   72      // bf16 row stride for staged tiles (16B-aligned rows, 2-way-free banks)
#define TSTR  84      // per-wave P scratch stride (bf16), conflict-free b128 reads
#define GROWS 192     // G ring rows (128 live + 64 staging)
#define OUT0  (16 * SEQ * HD)   // weights offset in d_out (output comes first)

__device__ __forceinline__ short f2bf(float x) {
    unsigned u = __float_as_uint(x);
    unsigned r = u + 0x7fffu + ((u >> 16) & 1u);   // RNE
    return (short)(r >> 16);
}

struct F16 { float4 a[4]; };   // 16 floats of prefetch state

__device__ __forceinline__ void cvt8(const float4& x, const float4& y, bf16x8& p) {
    p[0] = f2bf(x.x); p[1] = f2bf(x.y); p[2] = f2bf(x.z); p[3] = f2bf(x.w);
    p[4] = f2bf(y.x); p[5] = f2bf(y.y); p[6] = f2bf(y.z); p[7] = f2bf(y.w);
}

// ---- K/Q tile staging: issue loads early, convert+write late ----
__device__ __forceinline__ void issue64(const float* __restrict__ base, int tid, F16& f) {
    const int r = tid >> 2, cg = tid & 3;
    const float4* src = (const float4*)(base + (size_t)r * HD + cg * 16);
#pragma unroll
    for (int t = 0; t < 4; ++t) f.a[t] = src[t];
}
__device__ __forceinline__ void write64(short* __restrict__ dst, int tid, const F16& f) {
    const int r = tid >> 2, cg = tid & 3;
    bf16x8 p0, p1;
    cvt8(f.a[0], f.a[1], p0);
    cvt8(f.a[2], f.a[3], p1);
    *(bf16x8*)&dst[r * LDT + cg * 16]     = p0;
    *(bf16x8*)&dst[r * LDT + cg * 16 + 8] = p1;
}

// ---- G ring staging: 64 NEW rows per iteration (sliding window) ----
// new row ddn = r, value row e = etop - r, slot = (r + sbn) mod 192
__device__ __forceinline__ void issueG(const float* __restrict__ eg, int tid, int etop, F16& f) {
    const int r = tid >> 2, cg = tid & 3;
    const int e = etop - r;
    if (e >= 0 && e < 1024) {
        const float4* src = (const float4*)(eg + (size_t)e * HD + cg * 16);
#pragma unroll
        for (int t = 0; t < 4; ++t) f.a[t] = src[t];
    } else {
        const float4 z = make_float4(0.f, 0.f, 0.f, 0.f);
#pragma unroll
        for (int t = 0; t < 4; ++t) f.a[t] = z;
    }
}
__device__ __forceinline__ void writeG(short* __restrict__ Gr, int tid, int sbn, const F16& f) {
    const int r = tid >> 2, cg = tid & 3;
    int sl = r + sbn; if (sl >= GROWS) sl -= GROWS;
    bf16x8 p0, p1;
    cvt8(f.a[0], f.a[1], p0);
    cvt8(f.a[2], f.a[3], p1);
    *(bf16x8*)&Gr[sl * LDT + cg * 16]     = p0;
    *(bf16x8*)&Gr[sl * LDT + cg * 16 + 8] = p1;
}

// prologue: stage full 128-row window for kt=0 at slots (dd+128) mod 192
__device__ __forceinline__ void stageG_full(const float* __restrict__ eg, short* __restrict__ Gr,
                                            int tid, int i0) {
    const int dd = tid >> 1, hf = tid & 1;
    const int e = 1086 - i0 - dd;          // j0 = 0
    int sl = dd + 128; if (sl >= GROWS) sl -= GROWS;
    short* dst = &Gr[sl * LDT + hf * 32];
    if (e >= 0 && e < 1024) {
        const float4* src = (const float4*)(eg + (size_t)e * HD + hf * 32);
#pragma unroll
        for (int u = 0; u < 4; ++u) {
            bf16x8 p; cvt8(src[2 * u], src[2 * u + 1], p);
            *(bf16x8*)&dst[u * 8] = p;
        }
    } else {
        bf16x8 z = {0, 0, 0, 0, 0, 0, 0, 0};
#pragma unroll
        for (int u = 0; u < 4; ++u) *(bf16x8*)&dst[u * 8] = z;
    }
}

// ---- V staging: wave-uniform column group -> conflict-free transpose writes ----
__device__ __forceinline__ void issueV(const float* __restrict__ vbase, int tid, F16& f) {
    const int r = tid & 63, cg = tid >> 6;
    const float4* src = (const float4*)(vbase + (size_t)r * HD + cg * 16);
#pragma unroll
    for (int t = 0; t < 4; ++t) f.a[t] = src[t];
}
__device__ __forceinline__ void writeV(short* __restrict__ Vt, int tid, const F16& f) {
    const int r = tid & 63, cg = tid >> 6;
    const float* ff = (const float*)&f.a[0];
#pragma unroll
    for (int t = 0; t < 16; ++t)
        Vt[(cg * 16 + t) * LDT + r] = f2bf(ff[t]);
}

// S = Q@K^T + skewed rel; skew gather done in-register via partner-lane bpermute
__device__ __forceinline__ void compute_sc(const bf16x8* aq, const short* __restrict__ Ks,
                                           const short* __restrict__ Gr, int sb,
                                           int wv, int qd, int c, int lane,
                                           f32x4* sc, bool diag) {
    f32x4 tc[5];
    const f32x4 zz = {0.f, 0.f, 0.f, 0.f};
#pragma unroll
    for (int ct = 0; ct < 4; ++ct) sc[ct] = zz;
#pragma unroll
    for (int dt = 0; dt < 5; ++dt) tc[dt] = zz;
    int sl[5];
#pragma unroll
    for (int dt = 0; dt < 5; ++dt) {
        int s0 = (wv + dt) * 16 + sb + c;      // ring slot of G row (wv+dt)*16+c
        if (s0 >= GROWS) s0 -= GROWS;
        sl[dt] = s0 * LDT;
    }
#pragma unroll
    for (int s = 0; s < 2; ++s) {
        bf16x8 a = aq[s];
#pragma unroll
        for (int ct = 0; ct < 4; ++ct) {
            bf16x8 b = *(const bf16x8*)&Ks[(ct * 16 + c) * LDT + s * 32 + qd * 8];
            sc[ct] = __builtin_amdgcn_mfma_f32_16x16x32_bf16(a, b, sc[ct], 0, 0, 0);
        }
#pragma unroll
        for (int dt = 0; dt < 5; ++dt) {
            bf16x8 g = *(const bf16x8*)&Gr[sl[dt] + s * 32 + qd * 8];
            tc[dt] = __builtin_amdgcn_mfma_f32_16x16x32_bf16(a, g, tc[dt], 0, 0, 0);
        }
    }
    // T[rl][rl+63-jl] gather: partner c' = (rl+63-c)&15 (involution), each lane
    // SENDS the value its partner needs: tc[b4-ct][rg], b4 = (rl+63-c')>>4 in {3,4}
#pragma unroll
    for (int rg = 0; rg < 4; ++rg) {
        const int rl  = qd * 4 + rg;
        const int cp  = (rl + 63 - c) & 15;
        const int src = (lane & 48) | cp;
        const bool hi = (rl + 63 - cp) >= 64;
#pragma unroll
        for (int ct = 0; ct < 4; ++ct) {
            float vs = hi ? tc[4 - ct][rg] : tc[3 - ct][rg];
            float tr = __shfl(vs, src, 64);
            float sval = sc[ct][rg] + tr;
            if (diag && (ct * 16 + c > wv * 16 + rl)) sval = -3.0e38f;  // causal mask (diag tile only)
            sc[ct][rg] = sval;
        }
    }
}

__global__ __launch_bounds__(256, 2)
void relattn(const float* __restrict__ qg, const float* __restrict__ kg,
             const float* __restrict__ vg, const float* __restrict__ eg,
             float* __restrict__ outp)
{
    __shared__ short Ks2[2][64 * LDT];   // K double buffer
    __shared__ short Gr[GROWS * LDT];    // G sliding-window ring
    __shared__ short Vt2[2][64 * LDT];   // V^T double buffer
    __shared__ short Ps[4 * 16 * TSTR];  // per-wave P scratch

    const int tid  = threadIdx.x;
    const int wv   = tid >> 6;
    const int lane = tid & 63;
    const int qd   = lane >> 4;
    const int c    = lane & 15;

    const int bh = blockIdx.x & 15;
    const int u  = blockIdx.x >> 4;
    // blocks b and b+256 share a CU (round-robin XCD model): make qt(u)+qt(u+16)=31
    const int qt = (u < 16) ? u : 47 - u;
    const int i0 = qt * 64;

    float* Wg = outp + OUT0;

    // ---- zero-fill the fully-masked column region of weights ----
    {
        const int z0v = (qt + 1) * 16;   // first float4 column
        for (int r = 0; r < 64; ++r) {
            float4* dst = (float4*)(Wg + ((size_t)(bh * SEQ + i0 + r)) * SEQ);
            for (int jv = z0v + tid; jv < SEQ / 4; jv += 256)
                dst[jv] = make_float4(0.f, 0.f, 0.f, 0.f);
        }
    }

    // ---- stage Q through Ks2[0], preload A-fragments ----
    {
        F16 fq; issue64(qg + ((size_t)(bh * SEQ + i0)) * HD, tid, fq);
        write64(Ks2[0], tid, fq);
    }
    __syncthreads();
    bf16x8 aq[2];
#pragma unroll
    for (int s = 0; s < 2; ++s)
        aq[s] = *(const bf16x8*)&Ks2[0][(wv * 16 + c) * LDT + s * 32 + qd * 8];
    __syncthreads();

    float mrun[4], lrun[4];
#pragma unroll
    for (int rg = 0; rg < 4; ++rg) { mrun[rg] = -3.0e38f; lrun[rg] = 0.f; }

    // =================== PASS 1: row max / sum-exp ===================
    {
        F16 fk; issue64(kg + ((size_t)(bh * SEQ)) * HD, tid, fk);
        write64(Ks2[0], tid, fk);
        stageG_full(eg, Gr, tid, i0);
    }
    __syncthreads();
    int sb = 128;                               // ring base for kt=0
    for (int kt = 0; kt <= qt; ++kt) {
        const int cur = kt & 1;
        const bool pf = kt < qt;
        const int sbn = (sb >= 64) ? sb - 64 : sb + 128;   // ring base for kt+1
        F16 fk, fg;
        if (pf) {                                // issue next-tile loads early
            issue64(kg + ((size_t)(bh * SEQ + (kt + 1) * 64)) * HD, tid, fk);
            issueG(eg, tid, 1086 - i0 + 64 * (kt + 1), fg);
        }
        f32x4 sc[4];
        compute_sc(aq, Ks2[cur], Gr, sb, wv, qd, c, lane, sc, kt == qt);

#pragma unroll
        for (int rg = 0; rg < 4; ++rg) {
            float mx = fmaxf(fmaxf(sc[0][rg], sc[1][rg]), fmaxf(sc[2][rg], sc[3][rg]));
            mx = fmaxf(mx, __shfl_xor(mx, 1));
            mx = fmaxf(mx, __shfl_xor(mx, 2));
            mx = fmaxf(mx, __shfl_xor(mx, 4));
            mx = fmaxf(mx, __shfl_xor(mx, 8));
            const float mnew = fmaxf(mrun[rg], mx);
            float ss = __expf(sc[0][rg] - mnew) + __expf(sc[1][rg] - mnew)
                     + __expf(sc[2][rg] - mnew) + __expf(sc[3][rg] - mnew);
            ss += __shfl_xor(ss, 1);
            ss += __shfl_xor(ss, 2);
            ss += __shfl_xor(ss, 4);
            ss += __shfl_xor(ss, 8);
            lrun[rg] = lrun[rg] * __expf(mrun[rg] - mnew) + ss;
            mrun[rg] = mnew;
        }
        if (pf) {                                // convert+write late (latency hidden)
            write64(Ks2[cur ^ 1], tid, fk);
            writeG(Gr, tid, sbn, fg);            // targets dead ring slots only
        }
        sb = sbn;
        __syncthreads();                         // single barrier per k-tile
    }

    float linv[4];
#pragma unroll
    for (int rg = 0; rg < 4; ++rg) linv[rg] = 1.0f / lrun[rg];

    f32x4 ob[4];
    {
        const f32x4 zz = {0.f, 0.f, 0.f, 0.f};
#pragma unroll
        for (int dt = 0; dt < 4; ++dt) ob[dt] = zz;
    }

    // =================== PASS 2: write W, accumulate O ===================
    {
        F16 fk; issue64(kg + ((size_t)(bh * SEQ)) * HD, tid, fk);
        write64(Ks2[0], tid, fk);
        stageG_full(eg, Gr, tid, i0);
        F16 fv; issueV(vg + ((size_t)(bh * SEQ)) * HD, tid, fv);
        writeV(Vt2[0], tid, fv);
    }
    __syncthreads();
    sb = 128;
    short* Pw = &Ps[wv * 16 * TSTR];
    for (int kt = 0; kt <= qt; ++kt) {
        const int cur = kt & 1;
        const bool pf = kt < qt;
        const int sbn = (sb >= 64) ? sb - 64 : sb + 128;
        const int j0 = kt * 64;
        F16 fk, fg, fv;
        if (pf) {
            issue64(kg + ((size_t)(bh * SEQ + j0 + 64)) * HD, tid, fk);
            issueG(eg, tid, 1086 - i0 + j0 + 64, fg);
            issueV(vg + ((size_t)(bh * SEQ + j0 + 64)) * HD, tid, fv);
        }
        f32x4 sc[4];
        compute_sc(aq, Ks2[cur], Gr, sb, wv, qd, c, lane, sc, kt == qt);

        // W = exp(S - m) / l  -> global weights + wave-local P (bf16)
#pragma unroll
        for (int rg = 0; rg < 4; ++rg) {
            const int rl = qd * 4 + rg;
            const int ig = i0 + wv * 16 + rl;
            float* wrow = Wg + ((size_t)(bh * SEQ + ig)) * SEQ + j0;
#pragma unroll
            for (int ct = 0; ct < 4; ++ct) {
                const float w = __expf(sc[ct][rg] - mrun[rg]) * linv[rg];
                wrow[ct * 16 + c] = w;
                Pw[rl * TSTR + ct * 16 + c] = f2bf(w);
            }
        }

        // O += P @ V
#pragma unroll
        for (int s = 0; s < 2; ++s) {
            bf16x8 ap = *(const bf16x8*)&Pw[c * TSTR + s * 32 + qd * 8];
#pragma unroll
            for (int dt = 0; dt < 4; ++dt) {
                bf16x8 bv = *(const bf16x8*)&Vt2[cur][(dt * 16 + c) * LDT + s * 32 + qd * 8];
                ob[dt] = __builtin_amdgcn_mfma_f32_16x16x32_bf16(ap, bv, ob[dt], 0, 0, 0);
            }
        }
        if (pf) {
            write64(Ks2[cur ^ 1], tid, fk);
            writeG(Gr, tid, sbn, fg);
            writeV(Vt2[cur ^ 1], tid, fv);
        }
        sb = sbn;
        __syncthreads();
    }

    // ---- write O (already normalized, since P was normalized) ----
#pragma unroll
    for (int dt = 0; dt < 4; ++dt)
#pragma unroll
        for (int rg = 0; rg < 4; ++rg) {
            const int ig = i0 + wv * 16 + qd * 4 + rg;
            outp[((size_t)(bh * SEQ + ig)) * HD + dt * 16 + c] = ob[dt][rg];
        }
}

extern "C" void kernel_launch(void* const* d_in, const int* in_sizes, int n_in,
                              void* d_out, int out_size, void* d_ws, size_t ws_size,
                              hipStream_t stream) {
    const float* q = (const float*)d_in[0];
    const float* k = (const float*)d_in[1];
    const float* v = (const float*)d_in[2];
    const float* e = (const float*)d_in[3];
    // d_in[4] (mask) unused: causality computed from indices
    float* out = (float*)d_out;
    hipLaunchKernelGGL(relattn, dim3(512), dim3(256), 0, stream, q, k, v, e, out);
}